// Round 12
// baseline (307.611 us; speedup 1.0000x reference)
//
#include <hip/hip_runtime.h>
#include <hip/hip_bf16.h>

#define BN 4
#define TT 2305
#define CC 384
#define HH 6
#define DH 64
#define GW 48
#define BH (BN*HH)          // 24
#define TP 2368             // 37*64, padded T for K/V
#define TQP 2560            // q buffer rows
#define MF 9220             // BN*TT flattened tokens
#define MP 9344             // 73*128 padded
#define MB2 73              // m-blocks of 128 in out_gemm
#define NSPL 2              // flash split-K
#define QTI 19              // flash q-tiles of 128 rows
#define C2 0.07362223f      // 384^-0.5 * log2(e)

typedef __hip_bfloat16 bf16;
typedef __attribute__((ext_vector_type(8))) short short8;
typedef __attribute__((ext_vector_type(4))) float floatx4;
typedef __attribute__((ext_vector_type(16))) float floatx16;

#define MFMA16(a,b,c) __builtin_amdgcn_mfma_f32_16x16x32_bf16((a),(b),(c),0,0,0)
#define MFMA32(a,b,c) __builtin_amdgcn_mfma_f32_32x32x16_bf16((a),(b),(c),0,0,0)

__device__ __forceinline__ unsigned pack2(float a, float b) {
    bf16 lo = __float2bfloat16(a);
    bf16 hi = __float2bfloat16(b);
    unsigned short ul = *reinterpret_cast<unsigned short*>(&lo);
    unsigned short uh = *reinterpret_cast<unsigned short*>(&hi);
    return (unsigned)ul | ((unsigned)uh << 16);
}
__device__ __forceinline__ float bu2f(unsigned u16) {
    unsigned v = u16 << 16;
    return *reinterpret_cast<float*>(&v);
}

// ---------------------------------------------------------------------------
// K1: depthwise conv3x3 + BN (+ cls passthrough) + fused fp32->bf16 weight
// cvt. ROW-ALIGNED remap (r8, verified −7us).
// ---------------------------------------------------------------------------
__global__ __launch_bounds__(384)
void conv_bn(const float* __restrict__ x,
             const float* __restrict__ kq, const float* __restrict__ kk, const float* __restrict__ kv,
             const float* __restrict__ gq, const float* __restrict__ bq, const float* __restrict__ mq, const float* __restrict__ vq,
             const float* __restrict__ gk, const float* __restrict__ bk, const float* __restrict__ mk, const float* __restrict__ vk,
             const float* __restrict__ gv, const float* __restrict__ bv, const float* __restrict__ mv, const float* __restrict__ vv,
             const float* __restrict__ Wq, const float* __restrict__ Wk,
             const float* __restrict__ Wv, const float* __restrict__ Wo,
             bf16* __restrict__ wqb, bf16* __restrict__ wkb,
             bf16* __restrict__ wvb, bf16* __restrict__ wob,
             bf16* __restrict__ cq, bf16* __restrict__ ck, bf16* __restrict__ cv)
{
    {
        const int i = blockIdx.x * 384 + threadIdx.x;
        if (i < CC * CC) {
            wqb[i] = __float2bfloat16(Wq[i]);
            wkb[i] = __float2bfloat16(Wk[i]);
            wvb[i] = __float2bfloat16(Wv[i]);
            wob[i] = __float2bfloat16(Wo[i]);
        }
    }

    const int n = blockIdx.x;
    const int b = n / 289;
    const int idx = n % 289;
    const int c = threadIdx.x;
    const size_t xbase = (size_t)b * TT * CC;

    if (idx == 288) {
        bf16 xv = __float2bfloat16(x[xbase + c]);
        const size_t mrow = (size_t)(b * TT) * CC + c;
        cq[mrow] = xv; ck[mrow] = xv; cv[mrow] = xv;
        return;
    }

    const float sq = gq[c] * rsqrtf(vq[c] + 1e-5f), oq = bq[c] - mq[c] * sq;
    const float sk = gk[c] * rsqrtf(vk[c] + 1e-5f), ok = bk[c] - mk[c] * sk;
    const float sv = gv[c] * rsqrtf(vv[c] + 1e-5f), ov = bv[c] - mv[c] * sv;
    float wq9[9], wk9[9], wv9[9];
    #pragma unroll
    for (int u = 0; u < 9; u++) {
        wq9[u] = kq[c * 9 + u]; wk9[u] = kk[c * 9 + u]; wv9[u] = kv[c * 9 + u];
    }

    const int i = idx / 6;
    const int j0 = (idx % 6) * 8;

    float win[3][10];
    #pragma unroll
    for (int di = 0; di < 3; di++) {
        const int ii = i + di - 1;
        const bool rowok = (ii >= 0) && (ii < GW);
        #pragma unroll
        for (int wj = 0; wj < 10; wj++) {
            const int jj = j0 - 1 + wj;
            win[di][wj] = (rowok && jj >= 0 && jj < GW)
                ? x[xbase + (size_t)(1 + ii * GW + jj) * CC + c] : 0.f;
        }
    }

    #pragma unroll
    for (int g = 0; g < 8; g++) {
        float aq = 0.f, ak = 0.f, av = 0.f;
        #pragma unroll
        for (int di = 0; di < 3; di++)
            #pragma unroll
            for (int dj = 0; dj < 3; dj++) {
                const float xv = win[di][g + dj];
                const int u = di * 3 + dj;
                aq += xv * wq9[u]; ak += xv * wk9[u]; av += xv * wv9[u];
            }
        const int t = 1 + i * GW + j0 + g;
        const size_t mrow = (size_t)(b * TT + t) * CC + c;
        cq[mrow] = __float2bfloat16(aq * sq + oq);
        ck[mrow] = __float2bfloat16(ak * sk + ok);
        cv[mrow] = __float2bfloat16(av * sv + ov);
    }
}

// ---------------------------------------------------------------------------
// K2: QKV projection GEMM (r0 config, unchanged).
// ---------------------------------------------------------------------------
__global__ __launch_bounds__(256)
void qkv_gemm(const bf16* __restrict__ cq, const bf16* __restrict__ ck, const bf16* __restrict__ cv,
              const bf16* __restrict__ Wq, const bf16* __restrict__ Wk, const bf16* __restrict__ Wv,
              bf16* __restrict__ q, bf16* __restrict__ k, bf16* __restrict__ vT)
{
    const int bt = blockIdx.x;
    const int b = bt / 10;
    const int m0 = (bt % 10) * 256;
    const int n0 = blockIdx.y * 64;
    const int w = threadIdx.x >> 6, lane = threadIdx.x & 63;
    const int lm = lane & 15, q4 = lane >> 4;
    const int which = n0 / CC;
    const int obase = n0 % CC;
    const bf16* A = (which == 0) ? cq : (which == 1) ? ck : cv;
    const bf16* W = (which == 0) ? Wq : (which == 1) ? Wk : Wv;

    __shared__ __align__(16) bf16 TR[64 * 264];

    size_t arow[4];
    #pragma unroll
    for (int st = 0; st < 4; st++) {
        int t = m0 + st * 64 + w * 16 + lm;
        if (t >= TT) t = TT - 1;
        arow[st] = (size_t)(b * TT + t) * CC;
    }

    floatx4 acc[4][4];
    #pragma unroll
    for (int st = 0; st < 4; st++)
        #pragma unroll
        for (int n = 0; n < 4; n++) acc[st][n] = (floatx4){0.f, 0.f, 0.f, 0.f};

    #pragma unroll 2
    for (int kc = 0; kc < CC / 32; kc++) {
        short8 a[4];
        #pragma unroll
        for (int st = 0; st < 4; st++)
            a[st] = *(const short8*)(A + arow[st] + kc * 32 + q4 * 8);
        #pragma unroll
        for (int n = 0; n < 4; n++) {
            short8 bfr = *(const short8*)(W + (size_t)(obase + n * 16 + lm) * CC + kc * 32 + q4 * 8);
            #pragma unroll
            for (int st = 0; st < 4; st++)
                acc[st][n] = MFMA16(a[st], bfr, acc[st][n]);
        }
    }

    if (which == 2) {
        #pragma unroll
        for (int st = 0; st < 4; st++)
            #pragma unroll
            for (int n = 0; n < 4; n++) {
                const int ol = n * 16 + lm;
                const int ml = st * 64 + w * 16 + q4 * 4;
                uint2 pkd = { pack2(acc[st][n][0], acc[st][n][1]),
                              pack2(acc[st][n][2], acc[st][n][3]) };
                *(uint2*)&TR[ol * 264 + ml] = pkd;
            }
        __syncthreads();
        const int h = obase >> 6;
        const int o = threadIdx.x >> 2;
        const int seg = threadIdx.x & 3;
        const size_t vrow = ((size_t)(b * HH + h) * DH + o) * TP;
        #pragma unroll
        for (int j = 0; j < 8; j++) {
            const int ml = seg * 64 + j * 8;
            const int t = m0 + ml;
            uint4 val = *(const uint4*)&TR[o * 264 + ml];
            if (t + 8 <= TT) {
                *(uint4*)(vT + vrow + t) = val;
            } else if (t < TT) {
                const bf16* pv = (const bf16*)&val;
                for (int e = 0; e < 8 && t + e < TT; e++) vT[vrow + t + e] = pv[e];
            }
        }
    } else {
        #pragma unroll
        for (int st = 0; st < 4; st++)
            #pragma unroll
            for (int n = 0; n < 4; n++) {
                const int o = obase + n * 16 + lm;
                const int h = o >> 6, d = o & 63;
                #pragma unroll
                for (int r = 0; r < 4; r++) {
                    const int t = m0 + st * 64 + w * 16 + q4 * 4 + r;
                    if (t >= TT) continue;
                    bf16 val = __float2bfloat16(acc[st][n][r]);
                    if (which == 0)
                        q[((size_t)(b * HH + h) * TQP + t) * DH + d] = val;
                    else
                        k[((size_t)(b * HH + h) * TP + t) * DH + d] = val;
                }
            }
    }
}

// ---------------------------------------------------------------------------
// K3: flash attention, split-K x2, LDS-STAGED K/V, 4 waves x 32 q-rows at
// (256,4). r11 proved the LDS-staged structure at (256,3): 76.2us, VGPR 80,
// no spill, occupancy 21%. Remaining inefficiency: 12 waves/CU and grid 912
// > 768 slots = 1.19 scheduling rounds (tail visible as 21% time-avg
// occupancy). At (256,4): 16 waves/CU AND 912 <= 1024 slots -> single
// co-resident round. True live set = of(32 acc) + sv(32 acc) + qf(8) +
// staging(16) + addr(~15) ~= 110 <= 128-cap: the (256,3) build's 144 had
// slack the allocator never had to trim. Crush risk bounded: LDS operands
// mean lost ILP = serialized ds_reads (~120cy, counted-lgkmcnt pipelined)
// not serialized 900cy global loads (the r1/r5/r9 failure). LDS 4x34.8KB =
// 139KB <= 160 OK. Padded rows [64][68] -> <=2-way bank conflicts (free).
// REVERT CRITERION: flash > 76us or FETCH > 16 MB -> back to r11 (256,3).
// Numerics = r11's verified body (absmax .00244).
// ---------------------------------------------------------------------------
__global__ __launch_bounds__(256, 4)
void flash(const bf16* __restrict__ q, const bf16* __restrict__ k,
           const bf16* __restrict__ vT, bf16* __restrict__ OP, float* __restrict__ ML)
{
    const int id = blockIdx.x;
    const int bh = id % BH;
    const int rest = id / BH;
    const int z = rest % NSPL;
    const int qt = rest / NSPL;
    const int tid = threadIdx.x;
    const int w = tid >> 6, lane = tid & 63;
    const int q31 = lane & 31, hh = lane >> 5;
    const int q0 = qt * 128 + w * 32;
    const size_t kbase = (size_t)bh * TP * DH;
    const size_t qbase = (size_t)bh * TQP * DH;

    __shared__ __align__(16) bf16 Kl[2][64][68];
    __shared__ __align__(16) bf16 Vl[2][64][68];

    // cooperative staging indices: thread -> (row, 16B chunk)
    const int srow = tid >> 3;          // 0..31
    const int scol = (tid & 7) * 8;     // element col {0,8,...,56}

    // 37 k-tiles split 19/18
    const int tstart = z ? 19 : 0;
    const int tend   = z ? 37 : 19;

    int qr = q0 + q31;
    if (qr > TT - 1) qr = TT - 1;       // avoid uninitialized rows (defer-max)
    short8 qf[4];
    {
        const bf16* qrow = q + qbase + (size_t)qr * DH;
        #pragma unroll
        for (int kc = 0; kc < 4; kc++)
            qf[kc] = *(const short8*)(qrow + kc * 16 + hh * 8);
    }

    floatx16 of[2];
    #pragma unroll
    for (int dt = 0; dt < 2; dt++)
        #pragma unroll
        for (int r = 0; r < 16; r++) of[dt][r] = 0.f;
    float m2 = -1e30f, lsum = 0.f;

    // prologue: stage tile tstart into buffer 0
    {
        const bf16* kt = k + kbase + (size_t)tstart * 64 * DH;
        const bf16* vt = vT + kbase + tstart * 64;
        uint4 kr0 = *(const uint4*)(kt + (size_t)srow * DH + scol);
        uint4 kr1 = *(const uint4*)(kt + (size_t)(srow + 32) * DH + scol);
        uint4 vr0 = *(const uint4*)(vt + (size_t)srow * TP + scol);
        uint4 vr1 = *(const uint4*)(vt + (size_t)(srow + 32) * TP + scol);
        *(uint4*)&Kl[0][srow][scol]      = kr0;
        *(uint4*)&Kl[0][srow + 32][scol] = kr1;
        *(uint4*)&Vl[0][srow][scol]      = vr0;
        *(uint4*)&Vl[0][srow + 32][scol] = vr1;
    }
    __syncthreads();

    int cur = 0;
    #pragma unroll 1
    for (int tc = tstart; tc < tend; tc++) {
        const int t0 = tc * 64;
        const bool have_next = (tc + 1 < tend);

        // issue next tile's global loads NOW (latency hides under compute)
        uint4 kr0, kr1, vr0, vr1;
        if (have_next) {
            const bf16* kt = k + kbase + (size_t)(t0 + 64) * DH;
            const bf16* vt = vT + kbase + (t0 + 64);
            kr0 = *(const uint4*)(kt + (size_t)srow * DH + scol);
            kr1 = *(const uint4*)(kt + (size_t)(srow + 32) * DH + scol);
            vr0 = *(const uint4*)(vt + (size_t)srow * TP + scol);
            vr1 = *(const uint4*)(vt + (size_t)(srow + 32) * TP + scol);
        }

        // ---- compute from buffer cur (r11-verified body, LDS operands) ----
        short8 ka[2][4];
        #pragma unroll
        for (int mt = 0; mt < 2; mt++)
            #pragma unroll
            for (int kc = 0; kc < 4; kc++)
                ka[mt][kc] = *(const short8*)&Kl[cur][mt * 32 + q31][(2 * kc + hh) * 8];

        floatx16 sv[2];
        #pragma unroll
        for (int mt = 0; mt < 2; mt++)
            #pragma unroll
            for (int r = 0; r < 16; r++) sv[mt][r] = 0.f;
        __builtin_amdgcn_s_setprio(1);
        #pragma unroll
        for (int kc = 0; kc < 4; kc++) {
            sv[0] = MFMA32(ka[0][kc], qf[kc], sv[0]);
            sv[1] = MFMA32(ka[1][kc], qf[kc], sv[1]);
        }
        __builtin_amdgcn_s_setprio(0);

        short8 va[2][4];
        #pragma unroll
        for (int mt = 0; mt < 2; mt++)
            #pragma unroll
            for (int kc = 0; kc < 4; kc++)
                va[mt][kc] = *(const short8*)&Vl[cur][mt * 32 + q31][(2 * kc + hh) * 8];

        if (t0 + 64 > TT) {
            #pragma unroll
            for (int mt = 0; mt < 2; mt++)
                #pragma unroll
                for (int r = 0; r < 16; r++) {
                    const int tl = t0 + mt * 32 + (r & 3) + 8 * (r >> 2) + 4 * hh;
                    if (tl >= TT) sv[mt][r] = -1e30f;
                }
        }

        // tree row-max
        float r8[8];
        #pragma unroll
        for (int p = 0; p < 8; p++)
            r8[p] = fmaxf(fmaxf(sv[0][2 * p], sv[0][2 * p + 1]),
                          fmaxf(sv[1][2 * p], sv[1][2 * p + 1]));
        float rm = fmaxf(fmaxf(fmaxf(r8[0], r8[1]), fmaxf(r8[2], r8[3])),
                         fmaxf(fmaxf(r8[4], r8[5]), fmaxf(r8[6], r8[7])));
        rm = fmaxf(rm, __shfl_xor(rm, 32));
        const float rms = rm * C2;

        // defer-max (THR=8, log2 domain)
        if (!__all(rms <= m2 + 8.f)) {
            const float mn = fmaxf(m2, rms);
            const float alpha = __builtin_amdgcn_exp2f(m2 - mn);
            m2 = mn;
            lsum *= alpha;
            #pragma unroll
            for (int dt = 0; dt < 2; dt++)
                #pragma unroll
                for (int r = 0; r < 16; r++) of[dt][r] *= alpha;
        }
        const float negm = -m2;

        // exp2 + pack, row-sum in 4 parallel chains
        float rsp[4] = {0.f, 0.f, 0.f, 0.f};
        unsigned pk[2][8];
        #pragma unroll
        for (int mt = 0; mt < 2; mt++)
            #pragma unroll
            for (int p = 0; p < 8; p++) {
                const float p0 = __builtin_amdgcn_exp2f(fmaf(sv[mt][2 * p], C2, negm));
                const float p1 = __builtin_amdgcn_exp2f(fmaf(sv[mt][2 * p + 1], C2, negm));
                rsp[p & 3] += p0 + p1;
                pk[mt][p] = pack2(p0, p1);
            }
        float rs = (rsp[0] + rsp[1]) + (rsp[2] + rsp[3]);
        rs += __shfl_xor(rs, 32);
        lsum += rs;

        #pragma unroll
        for (int kc = 0; kc < 4; kc++) {
            const int u0 = 2 * kc, u1 = 2 * kc + 1;
            const unsigned P0a = pk[u0 >> 2][2 * (u0 & 3)];
            const unsigned P0b = pk[u0 >> 2][2 * (u0 & 3) + 1];
            const unsigned P1a = pk[u1 >> 2][2 * (u1 & 3)];
            const unsigned P1b = pk[u1 >> 2][2 * (u1 & 3) + 1];
            const unsigned X1 = hh ? P0a : P1a;
            const unsigned X2 = hh ? P0b : P1b;
            const unsigned Y1 = __shfl_xor(X1, 32);
            const unsigned Y2 = __shfl_xor(X2, 32);
            unsigned dw[4];
            dw[0] = hh ? Y1 : P0a;
            dw[1] = hh ? Y2 : P0b;
            dw[2] = hh ? P1a : Y1;
            dw[3] = hh ? P1b : Y2;
            short8 pb = *reinterpret_cast<short8*>(dw);
            __builtin_amdgcn_s_setprio(1);
            of[0] = MFMA32(va[0][kc], pb, of[0]);
            of[1] = MFMA32(va[1][kc], pb, of[1]);
            __builtin_amdgcn_s_setprio(0);
        }
        // ---- end compute ----

        // write next tile into the other buffer (loads landed during compute)
        if (have_next) {
            *(uint4*)&Kl[cur ^ 1][srow][scol]      = kr0;
            *(uint4*)&Kl[cur ^ 1][srow + 32][scol] = kr1;
            *(uint4*)&Vl[cur ^ 1][srow][scol]      = vr0;
            *(uint4*)&Vl[cur ^ 1][srow + 32][scol] = vr1;
        }
        __syncthreads();   // all waves done reading cur; buf cur^1 visible
        cur ^= 1;
    }

    // store unnormalized partials (rows packed to TT per (z,bh))
    const int qrow_s = q0 + q31;
    if (qrow_s < TT) {
        bf16* orow = OP + ((size_t)(z * BH + bh) * TT + qrow_s) * DH;
        #pragma unroll
        for (int dt = 0; dt < 2; dt++)
            #pragma unroll
            for (int p = 0; p < 4; p++) {
                const int d = dt * 32 + 8 * p + 4 * hh;
                unsigned lo = pack2(of[dt][4 * p], of[dt][4 * p + 1]);
                unsigned hi = pack2(of[dt][4 * p + 2], of[dt][4 * p + 3]);
                uint2 st = {lo, hi};
                *(uint2*)(orow + d) = st;
            }
        if (hh == 0) {
            float2 ml = {m2, lsum};
            *(float2*)&ML[((size_t)(z * BH + bh) * TT + qrow_s) * 2] = ml;
        }
    }
}

// ---------------------------------------------------------------------------
// K3b: merge the split-K partials -> att (bf16, head-major cols).
// ---------------------------------------------------------------------------
__global__ __launch_bounds__(256)
void merge(const bf16* __restrict__ OP, const float* __restrict__ ML,
           bf16* __restrict__ att)
{
    const int idx = blockIdx.x * 256 + threadIdx.x;
    if (idx >= BH * TT * 16) return;
    const int quad = idx & 15;
    const int pair = idx >> 4;
    const int bh = pair / TT, row = pair % TT;
    const int b = bh / HH, h = bh % HH;
    const int d0 = quad * 4;

    float2 ml[NSPL];
    #pragma unroll
    for (int z = 0; z < NSPL; z++)
        ml[z] = *(const float2*)&ML[((size_t)(z * BH + bh) * TT + row) * 2];
    float M = ml[0].x;
    #pragma unroll
    for (int z = 1; z < NSPL; z++) M = fmaxf(M, ml[z].x);
    float wz[NSPL], den = 0.f;
    #pragma unroll
    for (int z = 0; z < NSPL; z++) {
        wz[z] = __builtin_amdgcn_exp2f(ml[z].x - M);
        den += ml[z].y * wz[z];
    }
    const float inv = 1.f / den;

    float o0 = 0.f, o1 = 0.f, o2 = 0.f, o3 = 0.f;
    #pragma unroll
    for (int z = 0; z < NSPL; z++) {
        const float s = wz[z] * inv;
        const uint2 a = *(const uint2*)&OP[((size_t)(z * BH + bh) * TT + row) * DH + d0];
        o0 += bu2f(a.x & 0xffffu) * s;
        o1 += bu2f(a.x >> 16)     * s;
        o2 += bu2f(a.y & 0xffffu) * s;
        o3 += bu2f(a.y >> 16)     * s;
    }
    uint2 st = {pack2(o0, o1), pack2(o2, o3)};
    *(uint2*)&att[((size_t)(b * TT + row) * CC) + h * DH + d0] = st;
}

// ---------------------------------------------------------------------------
// K4: output projection GEMM + bias, 128-row m-tiles, fp32 out.
// ---------------------------------------------------------------------------
__global__ __launch_bounds__(256)
void out_gemm(const bf16* __restrict__ att, const bf16* __restrict__ Wo_bf,
              const float* __restrict__ bo, float* __restrict__ out)
{
    const int m0 = blockIdx.x * 128;
    const int n0 = blockIdx.y * 64;
    const int w = threadIdx.x >> 6, lane = threadIdx.x & 63;
    const int lm = lane & 15, q4 = lane >> 4;

    const size_t ar0 = (size_t)(m0 + w * 16 + lm) * CC;
    floatx4 acc[2][4];
    #pragma unroll
    for (int st = 0; st < 2; st++)
        #pragma unroll
        for (int n = 0; n < 4; n++) acc[st][n] = (floatx4){0.f, 0.f, 0.f, 0.f};

    #pragma unroll 4
    for (int kc = 0; kc < CC / 32; kc++) {
        short8 a0 = *(const short8*)(att + ar0 + kc * 32 + q4 * 8);
        short8 a1 = *(const short8*)(att + ar0 + (size_t)64 * CC + kc * 32 + q4 * 8);
        #pragma unroll
        for (int n = 0; n < 4; n++) {
            short8 bfr = *(const short8*)(Wo_bf + (size_t)(n0 + n * 16 + lm) * CC + kc * 32 + q4 * 8);
            acc[0][n] = MFMA16(a0, bfr, acc[0][n]);
            acc[1][n] = MFMA16(a1, bfr, acc[1][n]);
        }
    }

    #pragma unroll
    for (int st = 0; st < 2; st++)
        #pragma unroll
        for (int n = 0; n < 4; n++) {
            const int o = n0 + n * 16 + lm;
            const float bias = bo[o];
            #pragma unroll
            for (int r = 0; r < 4; r++) {
                const int m = m0 + st * 64 + w * 16 + q4 * 4 + r;
                if (m < MF) out[(size_t)m * CC + o] = acc[st][n][r] + bias;
            }
        }
}

// ---------------------------------------------------------------------------
extern "C" void kernel_launch(void* const* d_in, const int* in_sizes, int n_in,
                              void* d_out, int out_size, void* d_ws, size_t ws_size,
                              hipStream_t stream)
{
    const float* x  = (const float*)d_in[0];
    const float* kq = (const float*)d_in[3];
    const float* kk = (const float*)d_in[4];
    const float* kv = (const float*)d_in[5];
    const float* gq = (const float*)d_in[6];
    const float* bq = (const float*)d_in[7];
    const float* mq = (const float*)d_in[8];
    const float* vq = (const float*)d_in[9];
    const float* gk = (const float*)d_in[10];
    const float* bk = (const float*)d_in[11];
    const float* mk = (const float*)d_in[12];
    const float* vk = (const float*)d_in[13];
    const float* gv = (const float*)d_in[14];
    const float* bv = (const float*)d_in[15];
    const float* mv = (const float*)d_in[16];
    const float* vv = (const float*)d_in[17];
    const float* Wq = (const float*)d_in[18];
    const float* Wk = (const float*)d_in[19];
    const float* Wv = (const float*)d_in[20];
    const float* Wo = (const float*)d_in[21];
    const float* bo = (const float*)d_in[22];

    char* ws = (char*)d_ws;
    const size_t SZ_CONV = (size_t)MP * CC * 2;        // 7,176,192
    const size_t SZ_Q    = (size_t)BH * TQP * DH * 2;  // 7,864,320
    const size_t SZ_K    = (size_t)BH * TP * DH * 2;   // 7,274,496
    const size_t SZ_W    = (size_t)CC * CC * 2;        //   294,912
    size_t off = 0;
    bf16* cq   = (bf16*)(ws + off); off += SZ_CONV;
    bf16* ck   = (bf16*)(ws + off); off += SZ_CONV;
    bf16* cv   = (bf16*)(ws + off); off += SZ_CONV;
    bf16* qb   = (bf16*)(ws + off); off += SZ_Q;
    bf16* kb   = (bf16*)(ws + off); off += SZ_K;
    bf16* vTb  = (bf16*)(ws + off); off += SZ_K;
    bf16* attb = (bf16*)(ws + off); off += SZ_CONV;
    bf16* wqb  = (bf16*)(ws + off); off += SZ_W;
    bf16* wkb  = (bf16*)(ws + off); off += SZ_W;
    bf16* wvb  = (bf16*)(ws + off); off += SZ_W;
    bf16* wob  = (bf16*)(ws + off); off += SZ_W;
    // flash partials: OP aliases cq..cv (dead after qkv_gemm), ML in tail
    // NSPL*BH*TT*DH*2 = 14,161,920 <= 3*SZ_CONV = 21,528,576
    bf16*  OP = (bf16*)ws;
    float* ML = (float*)(ws + off); off += (size_t)NSPL * BH * TT * 2 * 4;

    conv_bn<<<BN * 289, 384, 0, stream>>>(x, kq, kk, kv,
                                          gq, bq, mq, vq,
                                          gk, bk, mk, vk,
                                          gv, bv, mv, vv,
                                          Wq, Wk, Wv, Wo,
                                          wqb, wkb, wvb, wob,
                                          cq, ck, cv);
    qkv_gemm<<<dim3(40, 18), 256, 0, stream>>>(cq, ck, cv, wqb, wkb, wvb, qb, kb, vTb);
    flash<<<QTI * NSPL * BH, 256, 0, stream>>>(qb, kb, vTb, OP, ML);
    merge<<<(BH * TT * 16 + 255) / 256, 256, 0, stream>>>(OP, ML, attb);
    out_gemm<<<dim3(MB2, 6), 256, 0, stream>>>(attb, wob, bo, (float*)d_out);
}

// Round 13
// 260.931 us; speedup vs baseline: 1.1789x; 1.1789x over previous
//
#include <hip/hip_runtime.h>
#include <hip/hip_bf16.h>

#define BN 4
#define TT 2305
#define CC 384
#define HH 6
#define DH 64
#define GW 48
#define BH (BN*HH)          // 24
#define TP 2368             // 37*64, padded T for K/V
#define TQP 2560            // q buffer rows
#define MF 9220             // BN*TT flattened tokens
#define MP 9344             // 73*128 padded
#define MB2 73              // m-blocks of 128 in out_gemm
#define NSPL 2              // flash split-K
#define QTI 19              // flash q-tiles of 128 rows
#define C2 0.07362223f      // 384^-0.5 * log2(e)

typedef __hip_bfloat16 bf16;
typedef __attribute__((ext_vector_type(8))) short short8;
typedef __attribute__((ext_vector_type(4))) float floatx4;
typedef __attribute__((ext_vector_type(16))) float floatx16;

#define MFMA16(a,b,c) __builtin_amdgcn_mfma_f32_16x16x32_bf16((a),(b),(c),0,0,0)
#define MFMA32(a,b,c) __builtin_amdgcn_mfma_f32_32x32x16_bf16((a),(b),(c),0,0,0)

__device__ __forceinline__ unsigned pack2(float a, float b) {
    bf16 lo = __float2bfloat16(a);
    bf16 hi = __float2bfloat16(b);
    unsigned short ul = *reinterpret_cast<unsigned short*>(&lo);
    unsigned short uh = *reinterpret_cast<unsigned short*>(&hi);
    return (unsigned)ul | ((unsigned)uh << 16);
}
__device__ __forceinline__ float bu2f(unsigned u16) {
    unsigned v = u16 << 16;
    return *reinterpret_cast<float*>(&v);
}

// ---------------------------------------------------------------------------
// K1: depthwise conv3x3 + BN (+ cls passthrough) + fused fp32->bf16 weight
// cvt. ROW-ALIGNED remap (r8, verified −7us).
// ---------------------------------------------------------------------------
__global__ __launch_bounds__(384)
void conv_bn(const float* __restrict__ x,
             const float* __restrict__ kq, const float* __restrict__ kk, const float* __restrict__ kv,
             const float* __restrict__ gq, const float* __restrict__ bq, const float* __restrict__ mq, const float* __restrict__ vq,
             const float* __restrict__ gk, const float* __restrict__ bk, const float* __restrict__ mk, const float* __restrict__ vk,
             const float* __restrict__ gv, const float* __restrict__ bv, const float* __restrict__ mv, const float* __restrict__ vv,
             const float* __restrict__ Wq, const float* __restrict__ Wk,
             const float* __restrict__ Wv, const float* __restrict__ Wo,
             bf16* __restrict__ wqb, bf16* __restrict__ wkb,
             bf16* __restrict__ wvb, bf16* __restrict__ wob,
             bf16* __restrict__ cq, bf16* __restrict__ ck, bf16* __restrict__ cv)
{
    {
        const int i = blockIdx.x * 384 + threadIdx.x;
        if (i < CC * CC) {
            wqb[i] = __float2bfloat16(Wq[i]);
            wkb[i] = __float2bfloat16(Wk[i]);
            wvb[i] = __float2bfloat16(Wv[i]);
            wob[i] = __float2bfloat16(Wo[i]);
        }
    }

    const int n = blockIdx.x;
    const int b = n / 289;
    const int idx = n % 289;
    const int c = threadIdx.x;
    const size_t xbase = (size_t)b * TT * CC;

    if (idx == 288) {
        bf16 xv = __float2bfloat16(x[xbase + c]);
        const size_t mrow = (size_t)(b * TT) * CC + c;
        cq[mrow] = xv; ck[mrow] = xv; cv[mrow] = xv;
        return;
    }

    const float sq = gq[c] * rsqrtf(vq[c] + 1e-5f), oq = bq[c] - mq[c] * sq;
    const float sk = gk[c] * rsqrtf(vk[c] + 1e-5f), ok = bk[c] - mk[c] * sk;
    const float sv = gv[c] * rsqrtf(vv[c] + 1e-5f), ov = bv[c] - mv[c] * sv;
    float wq9[9], wk9[9], wv9[9];
    #pragma unroll
    for (int u = 0; u < 9; u++) {
        wq9[u] = kq[c * 9 + u]; wk9[u] = kk[c * 9 + u]; wv9[u] = kv[c * 9 + u];
    }

    const int i = idx / 6;
    const int j0 = (idx % 6) * 8;

    float win[3][10];
    #pragma unroll
    for (int di = 0; di < 3; di++) {
        const int ii = i + di - 1;
        const bool rowok = (ii >= 0) && (ii < GW);
        #pragma unroll
        for (int wj = 0; wj < 10; wj++) {
            const int jj = j0 - 1 + wj;
            win[di][wj] = (rowok && jj >= 0 && jj < GW)
                ? x[xbase + (size_t)(1 + ii * GW + jj) * CC + c] : 0.f;
        }
    }

    #pragma unroll
    for (int g = 0; g < 8; g++) {
        float aq = 0.f, ak = 0.f, av = 0.f;
        #pragma unroll
        for (int di = 0; di < 3; di++)
            #pragma unroll
            for (int dj = 0; dj < 3; dj++) {
                const float xv = win[di][g + dj];
                const int u = di * 3 + dj;
                aq += xv * wq9[u]; ak += xv * wk9[u]; av += xv * wv9[u];
            }
        const int t = 1 + i * GW + j0 + g;
        const size_t mrow = (size_t)(b * TT + t) * CC + c;
        cq[mrow] = __float2bfloat16(aq * sq + oq);
        ck[mrow] = __float2bfloat16(ak * sk + ok);
        cv[mrow] = __float2bfloat16(av * sv + ov);
    }
}

// ---------------------------------------------------------------------------
// K2: QKV projection GEMM (r0 config, unchanged).
// ---------------------------------------------------------------------------
__global__ __launch_bounds__(256)
void qkv_gemm(const bf16* __restrict__ cq, const bf16* __restrict__ ck, const bf16* __restrict__ cv,
              const bf16* __restrict__ Wq, const bf16* __restrict__ Wk, const bf16* __restrict__ Wv,
              bf16* __restrict__ q, bf16* __restrict__ k, bf16* __restrict__ vT)
{
    const int bt = blockIdx.x;
    const int b = bt / 10;
    const int m0 = (bt % 10) * 256;
    const int n0 = blockIdx.y * 64;
    const int w = threadIdx.x >> 6, lane = threadIdx.x & 63;
    const int lm = lane & 15, q4 = lane >> 4;
    const int which = n0 / CC;
    const int obase = n0 % CC;
    const bf16* A = (which == 0) ? cq : (which == 1) ? ck : cv;
    const bf16* W = (which == 0) ? Wq : (which == 1) ? Wk : Wv;

    __shared__ __align__(16) bf16 TR[64 * 264];

    size_t arow[4];
    #pragma unroll
    for (int st = 0; st < 4; st++) {
        int t = m0 + st * 64 + w * 16 + lm;
        if (t >= TT) t = TT - 1;
        arow[st] = (size_t)(b * TT + t) * CC;
    }

    floatx4 acc[4][4];
    #pragma unroll
    for (int st = 0; st < 4; st++)
        #pragma unroll
        for (int n = 0; n < 4; n++) acc[st][n] = (floatx4){0.f, 0.f, 0.f, 0.f};

    #pragma unroll 2
    for (int kc = 0; kc < CC / 32; kc++) {
        short8 a[4];
        #pragma unroll
        for (int st = 0; st < 4; st++)
            a[st] = *(const short8*)(A + arow[st] + kc * 32 + q4 * 8);
        #pragma unroll
        for (int n = 0; n < 4; n++) {
            short8 bfr = *(const short8*)(W + (size_t)(obase + n * 16 + lm) * CC + kc * 32 + q4 * 8);
            #pragma unroll
            for (int st = 0; st < 4; st++)
                acc[st][n] = MFMA16(a[st], bfr, acc[st][n]);
        }
    }

    if (which == 2) {
        #pragma unroll
        for (int st = 0; st < 4; st++)
            #pragma unroll
            for (int n = 0; n < 4; n++) {
                const int ol = n * 16 + lm;
                const int ml = st * 64 + w * 16 + q4 * 4;
                uint2 pkd = { pack2(acc[st][n][0], acc[st][n][1]),
                              pack2(acc[st][n][2], acc[st][n][3]) };
                *(uint2*)&TR[ol * 264 + ml] = pkd;
            }
        __syncthreads();
        const int h = obase >> 6;
        const int o = threadIdx.x >> 2;
        const int seg = threadIdx.x & 3;
        const size_t vrow = ((size_t)(b * HH + h) * DH + o) * TP;
        #pragma unroll
        for (int j = 0; j < 8; j++) {
            const int ml = seg * 64 + j * 8;
            const int t = m0 + ml;
            uint4 val = *(const uint4*)&TR[o * 264 + ml];
            if (t + 8 <= TT) {
                *(uint4*)(vT + vrow + t) = val;
            } else if (t < TT) {
                const bf16* pv = (const bf16*)&val;
                for (int e = 0; e < 8 && t + e < TT; e++) vT[vrow + t + e] = pv[e];
            }
        }
    } else {
        #pragma unroll
        for (int st = 0; st < 4; st++)
            #pragma unroll
            for (int n = 0; n < 4; n++) {
                const int o = obase + n * 16 + lm;
                const int h = o >> 6, d = o & 63;
                #pragma unroll
                for (int r = 0; r < 4; r++) {
                    const int t = m0 + st * 64 + w * 16 + q4 * 4 + r;
                    if (t >= TT) continue;
                    bf16 val = __float2bfloat16(acc[st][n][r]);
                    if (which == 0)
                        q[((size_t)(b * HH + h) * TQP + t) * DH + d] = val;
                    else
                        k[((size_t)(b * HH + h) * TP + t) * DH + d] = val;
                }
            }
    }
}

// ---------------------------------------------------------------------------
// K3: flash attention, split-K x2, LDS-STAGED K/V, 4 waves x 32 q-rows at
// (256,3) — the r11 configuration, verified 76.2us / VGPR 80 / no spill.
// Occupancy ladder CLOSED: (256,2) global-load s-inner = 87us (r10);
// (256,3) LDS-staged = 76us (r11); (256,4) LDS-staged = SPILL (r12: VGPR 64,
// WRITE 260MB, 132us — staging regs' long live ranges push true need past
// the 128-cap). LDS staging sidesteps the r1/r5/r9 failure (hipcc refusing
// deep global-load pipelines under reg caps): operand fetch = ds_read_b128.
// Padded rows [64][68] -> <=2-way conflicts (free). One barrier per tile,
// block-uniform trip count; T14 async-STAGE (issue before compute, ds_write
// after). Grid 912 = 19 qt x 2 z x 24 bh at 3 blocks/CU.
// Numerics verified: absmax .00244.
// ---------------------------------------------------------------------------
__global__ __launch_bounds__(256, 3)
void flash(const bf16* __restrict__ q, const bf16* __restrict__ k,
           const bf16* __restrict__ vT, bf16* __restrict__ OP, float* __restrict__ ML)
{
    const int id = blockIdx.x;
    const int bh = id % BH;
    const int rest = id / BH;
    const int z = rest % NSPL;
    const int qt = rest / NSPL;
    const int tid = threadIdx.x;
    const int w = tid >> 6, lane = tid & 63;
    const int q31 = lane & 31, hh = lane >> 5;
    const int q0 = qt * 128 + w * 32;
    const size_t kbase = (size_t)bh * TP * DH;
    const size_t qbase = (size_t)bh * TQP * DH;

    __shared__ __align__(16) bf16 Kl[2][64][68];
    __shared__ __align__(16) bf16 Vl[2][64][68];

    // cooperative staging indices: thread -> (row, 16B chunk)
    const int srow = tid >> 3;          // 0..31
    const int scol = (tid & 7) * 8;     // element col {0,8,...,56}

    // 37 k-tiles split 19/18
    const int tstart = z ? 19 : 0;
    const int tend   = z ? 37 : 19;

    int qr = q0 + q31;
    if (qr > TT - 1) qr = TT - 1;       // avoid uninitialized rows (defer-max)
    short8 qf[4];
    {
        const bf16* qrow = q + qbase + (size_t)qr * DH;
        #pragma unroll
        for (int kc = 0; kc < 4; kc++)
            qf[kc] = *(const short8*)(qrow + kc * 16 + hh * 8);
    }

    floatx16 of[2];
    #pragma unroll
    for (int dt = 0; dt < 2; dt++)
        #pragma unroll
        for (int r = 0; r < 16; r++) of[dt][r] = 0.f;
    float m2 = -1e30f, lsum = 0.f;

    // prologue: stage tile tstart into buffer 0
    {
        const bf16* kt = k + kbase + (size_t)tstart * 64 * DH;
        const bf16* vt = vT + kbase + tstart * 64;
        uint4 kr0 = *(const uint4*)(kt + (size_t)srow * DH + scol);
        uint4 kr1 = *(const uint4*)(kt + (size_t)(srow + 32) * DH + scol);
        uint4 vr0 = *(const uint4*)(vt + (size_t)srow * TP + scol);
        uint4 vr1 = *(const uint4*)(vt + (size_t)(srow + 32) * TP + scol);
        *(uint4*)&Kl[0][srow][scol]      = kr0;
        *(uint4*)&Kl[0][srow + 32][scol] = kr1;
        *(uint4*)&Vl[0][srow][scol]      = vr0;
        *(uint4*)&Vl[0][srow + 32][scol] = vr1;
    }
    __syncthreads();

    int cur = 0;
    #pragma unroll 1
    for (int tc = tstart; tc < tend; tc++) {
        const int t0 = tc * 64;
        const bool have_next = (tc + 1 < tend);

        // issue next tile's global loads NOW (latency hides under compute)
        uint4 kr0, kr1, vr0, vr1;
        if (have_next) {
            const bf16* kt = k + kbase + (size_t)(t0 + 64) * DH;
            const bf16* vt = vT + kbase + (t0 + 64);
            kr0 = *(const uint4*)(kt + (size_t)srow * DH + scol);
            kr1 = *(const uint4*)(kt + (size_t)(srow + 32) * DH + scol);
            vr0 = *(const uint4*)(vt + (size_t)srow * TP + scol);
            vr1 = *(const uint4*)(vt + (size_t)(srow + 32) * TP + scol);
        }

        // ---- compute from buffer cur (verified body, LDS operands) ----
        short8 ka[2][4];
        #pragma unroll
        for (int mt = 0; mt < 2; mt++)
            #pragma unroll
            for (int kc = 0; kc < 4; kc++)
                ka[mt][kc] = *(const short8*)&Kl[cur][mt * 32 + q31][(2 * kc + hh) * 8];

        floatx16 sv[2];
        #pragma unroll
        for (int mt = 0; mt < 2; mt++)
            #pragma unroll
            for (int r = 0; r < 16; r++) sv[mt][r] = 0.f;
        __builtin_amdgcn_s_setprio(1);
        #pragma unroll
        for (int kc = 0; kc < 4; kc++) {
            sv[0] = MFMA32(ka[0][kc], qf[kc], sv[0]);
            sv[1] = MFMA32(ka[1][kc], qf[kc], sv[1]);
        }
        __builtin_amdgcn_s_setprio(0);

        short8 va[2][4];
        #pragma unroll
        for (int mt = 0; mt < 2; mt++)
            #pragma unroll
            for (int kc = 0; kc < 4; kc++)
                va[mt][kc] = *(const short8*)&Vl[cur][mt * 32 + q31][(2 * kc + hh) * 8];

        if (t0 + 64 > TT) {
            #pragma unroll
            for (int mt = 0; mt < 2; mt++)
                #pragma unroll
                for (int r = 0; r < 16; r++) {
                    const int tl = t0 + mt * 32 + (r & 3) + 8 * (r >> 2) + 4 * hh;
                    if (tl >= TT) sv[mt][r] = -1e30f;
                }
        }

        // tree row-max
        float r8[8];
        #pragma unroll
        for (int p = 0; p < 8; p++)
            r8[p] = fmaxf(fmaxf(sv[0][2 * p], sv[0][2 * p + 1]),
                          fmaxf(sv[1][2 * p], sv[1][2 * p + 1]));
        float rm = fmaxf(fmaxf(fmaxf(r8[0], r8[1]), fmaxf(r8[2], r8[3])),
                         fmaxf(fmaxf(r8[4], r8[5]), fmaxf(r8[6], r8[7])));
        rm = fmaxf(rm, __shfl_xor(rm, 32));
        const float rms = rm * C2;

        // defer-max (THR=8, log2 domain)
        if (!__all(rms <= m2 + 8.f)) {
            const float mn = fmaxf(m2, rms);
            const float alpha = __builtin_amdgcn_exp2f(m2 - mn);
            m2 = mn;
            lsum *= alpha;
            #pragma unroll
            for (int dt = 0; dt < 2; dt++)
                #pragma unroll
                for (int r = 0; r < 16; r++) of[dt][r] *= alpha;
        }
        const float negm = -m2;

        // exp2 + pack, row-sum in 4 parallel chains
        float rsp[4] = {0.f, 0.f, 0.f, 0.f};
        unsigned pk[2][8];
        #pragma unroll
        for (int mt = 0; mt < 2; mt++)
            #pragma unroll
            for (int p = 0; p < 8; p++) {
                const float p0 = __builtin_amdgcn_exp2f(fmaf(sv[mt][2 * p], C2, negm));
                const float p1 = __builtin_amdgcn_exp2f(fmaf(sv[mt][2 * p + 1], C2, negm));
                rsp[p & 3] += p0 + p1;
                pk[mt][p] = pack2(p0, p1);
            }
        float rs = (rsp[0] + rsp[1]) + (rsp[2] + rsp[3]);
        rs += __shfl_xor(rs, 32);
        lsum += rs;

        #pragma unroll
        for (int kc = 0; kc < 4; kc++) {
            const int u0 = 2 * kc, u1 = 2 * kc + 1;
            const unsigned P0a = pk[u0 >> 2][2 * (u0 & 3)];
            const unsigned P0b = pk[u0 >> 2][2 * (u0 & 3) + 1];
            const unsigned P1a = pk[u1 >> 2][2 * (u1 & 3)];
            const unsigned P1b = pk[u1 >> 2][2 * (u1 & 3) + 1];
            const unsigned X1 = hh ? P0a : P1a;
            const unsigned X2 = hh ? P0b : P1b;
            const unsigned Y1 = __shfl_xor(X1, 32);
            const unsigned Y2 = __shfl_xor(X2, 32);
            unsigned dw[4];
            dw[0] = hh ? Y1 : P0a;
            dw[1] = hh ? Y2 : P0b;
            dw[2] = hh ? P1a : Y1;
            dw[3] = hh ? P1b : Y2;
            short8 pb = *reinterpret_cast<short8*>(dw);
            __builtin_amdgcn_s_setprio(1);
            of[0] = MFMA32(va[0][kc], pb, of[0]);
            of[1] = MFMA32(va[1][kc], pb, of[1]);
            __builtin_amdgcn_s_setprio(0);
        }
        // ---- end compute ----

        // write next tile into the other buffer (loads landed during compute)
        if (have_next) {
            *(uint4*)&Kl[cur ^ 1][srow][scol]      = kr0;
            *(uint4*)&Kl[cur ^ 1][srow + 32][scol] = kr1;
            *(uint4*)&Vl[cur ^ 1][srow][scol]      = vr0;
            *(uint4*)&Vl[cur ^ 1][srow + 32][scol] = vr1;
        }
        __syncthreads();   // all waves done reading cur; buf cur^1 visible
        cur ^= 1;
    }

    // store unnormalized partials (rows packed to TT per (z,bh))
    const int qrow_s = q0 + q31;
    if (qrow_s < TT) {
        bf16* orow = OP + ((size_t)(z * BH + bh) * TT + qrow_s) * DH;
        #pragma unroll
        for (int dt = 0; dt < 2; dt++)
            #pragma unroll
            for (int p = 0; p < 4; p++) {
                const int d = dt * 32 + 8 * p + 4 * hh;
                unsigned lo = pack2(of[dt][4 * p], of[dt][4 * p + 1]);
                unsigned hi = pack2(of[dt][4 * p + 2], of[dt][4 * p + 3]);
                uint2 st = {lo, hi};
                *(uint2*)(orow + d) = st;
            }
        if (hh == 0) {
            float2 ml = {m2, lsum};
            *(float2*)&ML[((size_t)(z * BH + bh) * TT + qrow_s) * 2] = ml;
        }
    }
}

// ---------------------------------------------------------------------------
// K3b: merge the split-K partials -> att (bf16, head-major cols).
// ---------------------------------------------------------------------------
__global__ __launch_bounds__(256)
void merge(const bf16* __restrict__ OP, const float* __restrict__ ML,
           bf16* __restrict__ att)
{
    const int idx = blockIdx.x * 256 + threadIdx.x;
    if (idx >= BH * TT * 16) return;
    const int quad = idx & 15;
    const int pair = idx >> 4;
    const int bh = pair / TT, row = pair % TT;
    const int b = bh / HH, h = bh % HH;
    const int d0 = quad * 4;

    float2 ml[NSPL];
    #pragma unroll
    for (int z = 0; z < NSPL; z++)
        ml[z] = *(const float2*)&ML[((size_t)(z * BH + bh) * TT + row) * 2];
    float M = ml[0].x;
    #pragma unroll
    for (int z = 1; z < NSPL; z++) M = fmaxf(M, ml[z].x);
    float wz[NSPL], den = 0.f;
    #pragma unroll
    for (int z = 0; z < NSPL; z++) {
        wz[z] = __builtin_amdgcn_exp2f(ml[z].x - M);
        den += ml[z].y * wz[z];
    }
    const float inv = 1.f / den;

    float o0 = 0.f, o1 = 0.f, o2 = 0.f, o3 = 0.f;
    #pragma unroll
    for (int z = 0; z < NSPL; z++) {
        const float s = wz[z] * inv;
        const uint2 a = *(const uint2*)&OP[((size_t)(z * BH + bh) * TT + row) * DH + d0];
        o0 += bu2f(a.x & 0xffffu) * s;
        o1 += bu2f(a.x >> 16)     * s;
        o2 += bu2f(a.y & 0xffffu) * s;
        o3 += bu2f(a.y >> 16)     * s;
    }
    uint2 st = {pack2(o0, o1), pack2(o2, o3)};
    *(uint2*)&att[((size_t)(b * TT + row) * CC) + h * DH + d0] = st;
}

// ---------------------------------------------------------------------------
// K4: output projection GEMM + bias, 128-row m-tiles, fp32 out.
// ---------------------------------------------------------------------------
__global__ __launch_bounds__(256)
void out_gemm(const bf16* __restrict__ att, const bf16* __restrict__ Wo_bf,
              const float* __restrict__ bo, float* __restrict__ out)
{
    const int m0 = blockIdx.x * 128;
    const int n0 = blockIdx.y * 64;
    const int w = threadIdx.x >> 6, lane = threadIdx.x & 63;
    const int lm = lane & 15, q4 = lane >> 4;

    const size_t ar0 = (size_t)(m0 + w * 16 + lm) * CC;
    floatx4 acc[2][4];
    #pragma unroll
    for (int st = 0; st < 2; st++)
        #pragma unroll
        for (int n = 0; n < 4; n++) acc[st][n] = (floatx4){0.f, 0.f, 0.f, 0.f};

    #pragma unroll 4
    for (int kc = 0; kc < CC / 32; kc++) {
        short8 a0 = *(const short8*)(att + ar0 + kc * 32 + q4 * 8);
        short8 a1 = *(const short8*)(att + ar0 + (size_t)64 * CC + kc * 32 + q4 * 8);
        #pragma unroll
        for (int n = 0; n < 4; n++) {
            short8 bfr = *(const short8*)(Wo_bf + (size_t)(n0 + n * 16 + lm) * CC + kc * 32 + q4 * 8);
            acc[0][n] = MFMA16(a0, bfr, acc[0][n]);
            acc[1][n] = MFMA16(a1, bfr, acc[1][n]);
        }
    }

    #pragma unroll
    for (int st = 0; st < 2; st++)
        #pragma unroll
        for (int n = 0; n < 4; n++) {
            const int o = n0 + n * 16 + lm;
            const float bias = bo[o];
            #pragma unroll
            for (int r = 0; r < 4; r++) {
                const int m = m0 + st * 64 + w * 16 + q4 * 4 + r;
                if (m < MF) out[(size_t)m * CC + o] = acc[st][n][r] + bias;
            }
        }
}

// ---------------------------------------------------------------------------
extern "C" void kernel_launch(void* const* d_in, const int* in_sizes, int n_in,
                              void* d_out, int out_size, void* d_ws, size_t ws_size,
                              hipStream_t stream)
{
    const float* x  = (const float*)d_in[0];
    const float* kq = (const float*)d_in[3];
    const float* kk = (const float*)d_in[4];
    const float* kv = (const float*)d_in[5];
    const float* gq = (const float*)d_in[6];
    const float* bq = (const float*)d_in[7];
    const float* mq = (const float*)d_in[8];
    const float* vq = (const float*)d_in[9];
    const float* gk = (const float*)d_in[10];
    const float* bk = (const float*)d_in[11];
    const float* mk = (const float*)d_in[12];
    const float* vk = (const float*)d_in[13];
    const float* gv = (const float*)d_in[14];
    const float* bv = (const float*)d_in[15];
    const float* mv = (const float*)d_in[16];
    const float* vv = (const float*)d_in[17];
    const float* Wq = (const float*)d_in[18];
    const float* Wk = (const float*)d_in[19];
    const float* Wv = (const float*)d_in[20];
    const float* Wo = (const float*)d_in[21];
    const float* bo = (const float*)d_in[22];

    char* ws = (char*)d_ws;
    const size_t SZ_CONV = (size_t)MP * CC * 2;        // 7,176,192
    const size_t SZ_Q    = (size_t)BH * TQP * DH * 2;  // 7,864,320
    const size_t SZ_K    = (size_t)BH * TP * DH * 2;   // 7,274,496
    const size_t SZ_W    = (size_t)CC * CC * 2;        //   294,912
    size_t off = 0;
    bf16* cq   = (bf16*)(ws + off); off += SZ_CONV;
    bf16* ck   = (bf16*)(ws + off); off += SZ_CONV;
    bf16* cv   = (bf16*)(ws + off); off += SZ_CONV;
    bf16* qb   = (bf16*)(ws + off); off += SZ_Q;
    bf16* kb   = (bf16*)(ws + off); off += SZ_K;
    bf16* vTb  = (bf16*)(ws + off); off += SZ_K;
    bf16* attb = (bf16*)(ws + off); off += SZ_CONV;
    bf16* wqb  = (bf16*)(ws + off); off += SZ_W;
    bf16* wkb  = (bf16*)(ws + off); off += SZ_W;
    bf16* wvb  = (bf16*)(ws + off); off += SZ_W;
    bf16* wob  = (bf16*)(ws + off); off += SZ_W;
    // flash partials: OP aliases cq..cv (dead after qkv_gemm), ML in tail
    // NSPL*BH*TT*DH*2 = 14,161,920 <= 3*SZ_CONV = 21,528,576
    bf16*  OP = (bf16*)ws;
    float* ML = (float*)(ws + off); off += (size_t)NSPL * BH * TT * 2 * 4;

    conv_bn<<<BN * 289, 384, 0, stream>>>(x, kq, kk, kv,
                                          gq, bq, mq, vq,
                                          gk, bk, mk, vk,
                                          gv, bv, mv, vv,
                                          Wq, Wk, Wv, Wo,
                                          wqb, wkb, wvb, wob,
                                          cq, ck, cv);
    qkv_gemm<<<dim3(40, 18), 256, 0, stream>>>(cq, ck, cv, wqb, wkb, wvb, qb, kb, vTb);
    flash<<<QTI * NSPL * BH, 256, 0, stream>>>(qb, kb, vTb, OP, ML);
    merge<<<(BH * TT * 16 + 255) / 256, 256, 0, stream>>>(OP, ML, attb);
    out_gemm<<<dim3(MB2, 6), 256, 0, stream>>>(attb, wob, bo, (float*)d_out);
}

// Round 14
// 250.304 us; speedup vs baseline: 1.2289x; 1.0425x over previous
//
#include <hip/hip_runtime.h>
#include <hip/hip_bf16.h>

#define BN 4
#define TT 2305
#define CC 384
#define HH 6
#define DH 64
#define GW 48
#define BH (BN*HH)          // 24
#define TP 2368             // 37*64, padded T for K/V
#define TQP 2560            // q buffer rows (10*256 coverage)
#define MF 9220             // BN*TT flattened tokens
#define MP 9344             // 73*128 padded
#define MB2 73              // m-blocks of 128 in out_gemm
#define NSPL 2              // flash split-K
#define QTI 10              // flash q-tiles of 256 rows
#define C2 0.07362223f      // 384^-0.5 * log2(e)

typedef __hip_bfloat16 bf16;
typedef __attribute__((ext_vector_type(8))) short short8;
typedef __attribute__((ext_vector_type(4))) float floatx4;
typedef __attribute__((ext_vector_type(16))) float floatx16;

#define MFMA16(a,b,c) __builtin_amdgcn_mfma_f32_16x16x32_bf16((a),(b),(c),0,0,0)
#define MFMA32(a,b,c) __builtin_amdgcn_mfma_f32_32x32x16_bf16((a),(b),(c),0,0,0)

__device__ __forceinline__ unsigned pack2(float a, float b) {
    bf16 lo = __float2bfloat16(a);
    bf16 hi = __float2bfloat16(b);
    unsigned short ul = *reinterpret_cast<unsigned short*>(&lo);
    unsigned short uh = *reinterpret_cast<unsigned short*>(&hi);
    return (unsigned)ul | ((unsigned)uh << 16);
}
__device__ __forceinline__ float bu2f(unsigned u16) {
    unsigned v = u16 << 16;
    return *reinterpret_cast<float*>(&v);
}

// ---------------------------------------------------------------------------
// K1: depthwise conv3x3 + BN (+ cls passthrough) + fused fp32->bf16 weight
// cvt. ROW-ALIGNED remap (r8, verified −7us).
// ---------------------------------------------------------------------------
__global__ __launch_bounds__(384)
void conv_bn(const float* __restrict__ x,
             const float* __restrict__ kq, const float* __restrict__ kk, const float* __restrict__ kv,
             const float* __restrict__ gq, const float* __restrict__ bq, const float* __restrict__ mq, const float* __restrict__ vq,
             const float* __restrict__ gk, const float* __restrict__ bk, const float* __restrict__ mk, const float* __restrict__ vk,
             const float* __restrict__ gv, const float* __restrict__ bv, const float* __restrict__ mv, const float* __restrict__ vv,
             const float* __restrict__ Wq, const float* __restrict__ Wk,
             const float* __restrict__ Wv, const float* __restrict__ Wo,
             bf16* __restrict__ wqb, bf16* __restrict__ wkb,
             bf16* __restrict__ wvb, bf16* __restrict__ wob,
             bf16* __restrict__ cq, bf16* __restrict__ ck, bf16* __restrict__ cv)
{
    {
        const int i = blockIdx.x * 384 + threadIdx.x;
        if (i < CC * CC) {
            wqb[i] = __float2bfloat16(Wq[i]);
            wkb[i] = __float2bfloat16(Wk[i]);
            wvb[i] = __float2bfloat16(Wv[i]);
            wob[i] = __float2bfloat16(Wo[i]);
        }
    }

    const int n = blockIdx.x;
    const int b = n / 289;
    const int idx = n % 289;
    const int c = threadIdx.x;
    const size_t xbase = (size_t)b * TT * CC;

    if (idx == 288) {
        bf16 xv = __float2bfloat16(x[xbase + c]);
        const size_t mrow = (size_t)(b * TT) * CC + c;
        cq[mrow] = xv; ck[mrow] = xv; cv[mrow] = xv;
        return;
    }

    const float sq = gq[c] * rsqrtf(vq[c] + 1e-5f), oq = bq[c] - mq[c] * sq;
    const float sk = gk[c] * rsqrtf(vk[c] + 1e-5f), ok = bk[c] - mk[c] * sk;
    const float sv = gv[c] * rsqrtf(vv[c] + 1e-5f), ov = bv[c] - mv[c] * sv;
    float wq9[9], wk9[9], wv9[9];
    #pragma unroll
    for (int u = 0; u < 9; u++) {
        wq9[u] = kq[c * 9 + u]; wk9[u] = kk[c * 9 + u]; wv9[u] = kv[c * 9 + u];
    }

    const int i = idx / 6;
    const int j0 = (idx % 6) * 8;

    float win[3][10];
    #pragma unroll
    for (int di = 0; di < 3; di++) {
        const int ii = i + di - 1;
        const bool rowok = (ii >= 0) && (ii < GW);
        #pragma unroll
        for (int wj = 0; wj < 10; wj++) {
            const int jj = j0 - 1 + wj;
            win[di][wj] = (rowok && jj >= 0 && jj < GW)
                ? x[xbase + (size_t)(1 + ii * GW + jj) * CC + c] : 0.f;
        }
    }

    #pragma unroll
    for (int g = 0; g < 8; g++) {
        float aq = 0.f, ak = 0.f, av = 0.f;
        #pragma unroll
        for (int di = 0; di < 3; di++)
            #pragma unroll
            for (int dj = 0; dj < 3; dj++) {
                const float xv = win[di][g + dj];
                const int u = di * 3 + dj;
                aq += xv * wq9[u]; ak += xv * wk9[u]; av += xv * wv9[u];
            }
        const int t = 1 + i * GW + j0 + g;
        const size_t mrow = (size_t)(b * TT + t) * CC + c;
        cq[mrow] = __float2bfloat16(aq * sq + oq);
        ck[mrow] = __float2bfloat16(ak * sk + ok);
        cv[mrow] = __float2bfloat16(av * sv + ov);
    }
}

// ---------------------------------------------------------------------------
// K2: QKV projection GEMM (r0 config, unchanged).
// ---------------------------------------------------------------------------
__global__ __launch_bounds__(256)
void qkv_gemm(const bf16* __restrict__ cq, const bf16* __restrict__ ck, const bf16* __restrict__ cv,
              const bf16* __restrict__ Wq, const bf16* __restrict__ Wk, const bf16* __restrict__ Wv,
              bf16* __restrict__ q, bf16* __restrict__ k, bf16* __restrict__ vT)
{
    const int bt = blockIdx.x;
    const int b = bt / 10;
    const int m0 = (bt % 10) * 256;
    const int n0 = blockIdx.y * 64;
    const int w = threadIdx.x >> 6, lane = threadIdx.x & 63;
    const int lm = lane & 15, q4 = lane >> 4;
    const int which = n0 / CC;
    const int obase = n0 % CC;
    const bf16* A = (which == 0) ? cq : (which == 1) ? ck : cv;
    const bf16* W = (which == 0) ? Wq : (which == 1) ? Wk : Wv;

    __shared__ __align__(16) bf16 TR[64 * 264];

    size_t arow[4];
    #pragma unroll
    for (int st = 0; st < 4; st++) {
        int t = m0 + st * 64 + w * 16 + lm;
        if (t >= TT) t = TT - 1;
        arow[st] = (size_t)(b * TT + t) * CC;
    }

    floatx4 acc[4][4];
    #pragma unroll
    for (int st = 0; st < 4; st++)
        #pragma unroll
        for (int n = 0; n < 4; n++) acc[st][n] = (floatx4){0.f, 0.f, 0.f, 0.f};

    #pragma unroll 2
    for (int kc = 0; kc < CC / 32; kc++) {
        short8 a[4];
        #pragma unroll
        for (int st = 0; st < 4; st++)
            a[st] = *(const short8*)(A + arow[st] + kc * 32 + q4 * 8);
        #pragma unroll
        for (int n = 0; n < 4; n++) {
            short8 bfr = *(const short8*)(W + (size_t)(obase + n * 16 + lm) * CC + kc * 32 + q4 * 8);
            #pragma unroll
            for (int st = 0; st < 4; st++)
                acc[st][n] = MFMA16(a[st], bfr, acc[st][n]);
        }
    }

    if (which == 2) {
        #pragma unroll
        for (int st = 0; st < 4; st++)
            #pragma unroll
            for (int n = 0; n < 4; n++) {
                const int ol = n * 16 + lm;
                const int ml = st * 64 + w * 16 + q4 * 4;
                uint2 pkd = { pack2(acc[st][n][0], acc[st][n][1]),
                              pack2(acc[st][n][2], acc[st][n][3]) };
                *(uint2*)&TR[ol * 264 + ml] = pkd;
            }
        __syncthreads();
        const int h = obase >> 6;
        const int o = threadIdx.x >> 2;
        const int seg = threadIdx.x & 3;
        const size_t vrow = ((size_t)(b * HH + h) * DH + o) * TP;
        #pragma unroll
        for (int j = 0; j < 8; j++) {
            const int ml = seg * 64 + j * 8;
            const int t = m0 + ml;
            uint4 val = *(const uint4*)&TR[o * 264 + ml];
            if (t + 8 <= TT) {
                *(uint4*)(vT + vrow + t) = val;
            } else if (t < TT) {
                const bf16* pv = (const bf16*)&val;
                for (int e = 0; e < 8 && t + e < TT; e++) vT[vrow + t + e] = pv[e];
            }
        }
    } else {
        #pragma unroll
        for (int st = 0; st < 4; st++)
            #pragma unroll
            for (int n = 0; n < 4; n++) {
                const int o = obase + n * 16 + lm;
                const int h = o >> 6, d = o & 63;
                #pragma unroll
                for (int r = 0; r < 4; r++) {
                    const int t = m0 + st * 64 + w * 16 + q4 * 4 + r;
                    if (t >= TT) continue;
                    bf16 val = __float2bfloat16(acc[st][n][r]);
                    if (which == 0)
                        q[((size_t)(b * HH + h) * TQP + t) * DH + d] = val;
                    else
                        k[((size_t)(b * HH + h) * TP + t) * DH + d] = val;
                }
            }
    }
}

// ---------------------------------------------------------------------------
// K3: flash attention, split-K x2, LDS-STAGED K/V + s-INNER (4 waves x 64
// q-rows) at (256,2). Combines the two verified wins: r11's LDS staging
// (76->74us at 128-row blocks; removed the global-load-pipeline register
// bottleneck) and r10's s-inner reuse (each staged tile + ka/va register
// fragments feed TWO 32-row softmax chains -> staging traffic and barriers
// per q-row HALVE, plus cross-s ILP). Grid 480 = 10 qt x 2 z x 24 bh at
// 2 blocks/CU <= 512 slots: SINGLE co-resident round (r11's 1.19-round
// tail gone). Register ledger: ka(32)+va(32)+qf(16)+of-acc(64 AGPR)+
// sv(32 transient)+staging(16)+addr(~12) ~= 204 <= 256-cap; min_waves=2
// has never triggered the allocator crush (r0/r4/r7/r10). LDS 2x34.8KB =
// 69.6KB/CU. Padded rows [64][68] -> <=2-way conflicts (free).
// REVERT CRITERION: flash >= 74us or WRITE >> 15MB (spill) -> back to r11.
// Numerics = verified body (absmax .00244).
// ---------------------------------------------------------------------------
__global__ __launch_bounds__(256, 2)
void flash(const bf16* __restrict__ q, const bf16* __restrict__ k,
           const bf16* __restrict__ vT, bf16* __restrict__ OP, float* __restrict__ ML)
{
    const int id = blockIdx.x;
    const int bh = id % BH;
    const int rest = id / BH;
    const int z = rest % NSPL;
    const int qt = rest / NSPL;
    const int tid = threadIdx.x;
    const int w = tid >> 6, lane = tid & 63;
    const int q31 = lane & 31, hh = lane >> 5;
    const int q0 = qt * 256 + w * 64;
    const size_t kbase = (size_t)bh * TP * DH;
    const size_t qbase = (size_t)bh * TQP * DH;

    __shared__ __align__(16) bf16 Kl[2][64][68];
    __shared__ __align__(16) bf16 Vl[2][64][68];

    // cooperative staging indices: thread -> (row, 16B chunk)
    const int srow = tid >> 3;          // 0..31
    const int scol = (tid & 7) * 8;     // element col {0,8,...,56}

    // 37 k-tiles split 19/18
    const int tstart = z ? 19 : 0;
    const int tend   = z ? 37 : 19;

    short8 qf[2][4];
    #pragma unroll
    for (int s = 0; s < 2; s++) {
        int qr = q0 + s * 32 + q31;
        if (qr > TT - 1) qr = TT - 1;   // avoid uninitialized rows (defer-max)
        const bf16* qrow = q + qbase + (size_t)qr * DH;
        #pragma unroll
        for (int kc = 0; kc < 4; kc++)
            qf[s][kc] = *(const short8*)(qrow + kc * 16 + hh * 8);
    }

    floatx16 of[2][2];
    #pragma unroll
    for (int s = 0; s < 2; s++)
        #pragma unroll
        for (int dt = 0; dt < 2; dt++)
            #pragma unroll
            for (int r = 0; r < 16; r++) of[s][dt][r] = 0.f;
    float m2[2] = {-1e30f, -1e30f}, lsum[2] = {0.f, 0.f};

    // prologue: stage tile tstart into buffer 0
    {
        const bf16* kt = k + kbase + (size_t)tstart * 64 * DH;
        const bf16* vt = vT + kbase + tstart * 64;
        uint4 kr0 = *(const uint4*)(kt + (size_t)srow * DH + scol);
        uint4 kr1 = *(const uint4*)(kt + (size_t)(srow + 32) * DH + scol);
        uint4 vr0 = *(const uint4*)(vt + (size_t)srow * TP + scol);
        uint4 vr1 = *(const uint4*)(vt + (size_t)(srow + 32) * TP + scol);
        *(uint4*)&Kl[0][srow][scol]      = kr0;
        *(uint4*)&Kl[0][srow + 32][scol] = kr1;
        *(uint4*)&Vl[0][srow][scol]      = vr0;
        *(uint4*)&Vl[0][srow + 32][scol] = vr1;
    }
    __syncthreads();

    int cur = 0;
    #pragma unroll 1
    for (int tc = tstart; tc < tend; tc++) {
        const int t0 = tc * 64;
        const bool have_next = (tc + 1 < tend);

        // issue next tile's global loads NOW (latency hides under compute)
        uint4 kr0, kr1, vr0, vr1;
        if (have_next) {
            const bf16* kt = k + kbase + (size_t)(t0 + 64) * DH;
            const bf16* vt = vT + kbase + (t0 + 64);
            kr0 = *(const uint4*)(kt + (size_t)srow * DH + scol);
            kr1 = *(const uint4*)(kt + (size_t)(srow + 32) * DH + scol);
            vr0 = *(const uint4*)(vt + (size_t)srow * TP + scol);
            vr1 = *(const uint4*)(vt + (size_t)(srow + 32) * TP + scol);
        }

        // LDS -> register fragments ONCE per tile, shared by both s-chains
        short8 ka[2][4], va[2][4];
        #pragma unroll
        for (int mt = 0; mt < 2; mt++)
            #pragma unroll
            for (int kc = 0; kc < 4; kc++) {
                ka[mt][kc] = *(const short8*)&Kl[cur][mt * 32 + q31][(2 * kc + hh) * 8];
                va[mt][kc] = *(const short8*)&Vl[cur][mt * 32 + q31][(2 * kc + hh) * 8];
            }
        const bool tail = (t0 + 64 > TT);

        #pragma unroll
        for (int s = 0; s < 2; s++) {
            floatx16 sv[2];
            #pragma unroll
            for (int mt = 0; mt < 2; mt++)
                #pragma unroll
                for (int r = 0; r < 16; r++) sv[mt][r] = 0.f;
            __builtin_amdgcn_s_setprio(1);
            #pragma unroll
            for (int kc = 0; kc < 4; kc++) {
                sv[0] = MFMA32(ka[0][kc], qf[s][kc], sv[0]);
                sv[1] = MFMA32(ka[1][kc], qf[s][kc], sv[1]);
            }
            __builtin_amdgcn_s_setprio(0);
            if (tail) {
                #pragma unroll
                for (int mt = 0; mt < 2; mt++)
                    #pragma unroll
                    for (int r = 0; r < 16; r++) {
                        const int tl = t0 + mt * 32 + (r & 3) + 8 * (r >> 2) + 4 * hh;
                        if (tl >= TT) sv[mt][r] = -1e30f;
                    }
            }
            // tree row-max
            float r8[8];
            #pragma unroll
            for (int p = 0; p < 8; p++)
                r8[p] = fmaxf(fmaxf(sv[0][2 * p], sv[0][2 * p + 1]),
                              fmaxf(sv[1][2 * p], sv[1][2 * p + 1]));
            float rm = fmaxf(fmaxf(fmaxf(r8[0], r8[1]), fmaxf(r8[2], r8[3])),
                             fmaxf(fmaxf(r8[4], r8[5]), fmaxf(r8[6], r8[7])));
            rm = fmaxf(rm, __shfl_xor(rm, 32));
            const float rms = rm * C2;

            // defer-max (THR=8, log2 domain)
            if (!__all(rms <= m2[s] + 8.f)) {
                const float mn = fmaxf(m2[s], rms);
                const float alpha = __builtin_amdgcn_exp2f(m2[s] - mn);
                m2[s] = mn;
                lsum[s] *= alpha;
                #pragma unroll
                for (int dt = 0; dt < 2; dt++)
                    #pragma unroll
                    for (int r = 0; r < 16; r++) of[s][dt][r] *= alpha;
            }
            const float negm = -m2[s];

            // exp2 + pack, row-sum in 4 parallel chains
            float rsp[4] = {0.f, 0.f, 0.f, 0.f};
            unsigned pk[2][8];
            #pragma unroll
            for (int mt = 0; mt < 2; mt++)
                #pragma unroll
                for (int p = 0; p < 8; p++) {
                    const float p0 = __builtin_amdgcn_exp2f(fmaf(sv[mt][2 * p], C2, negm));
                    const float p1 = __builtin_amdgcn_exp2f(fmaf(sv[mt][2 * p + 1], C2, negm));
                    rsp[p & 3] += p0 + p1;
                    pk[mt][p] = pack2(p0, p1);
                }
            float rs = (rsp[0] + rsp[1]) + (rsp[2] + rsp[3]);
            rs += __shfl_xor(rs, 32);
            lsum[s] += rs;

            #pragma unroll
            for (int kc = 0; kc < 4; kc++) {
                const int u0 = 2 * kc, u1 = 2 * kc + 1;
                const unsigned P0a = pk[u0 >> 2][2 * (u0 & 3)];
                const unsigned P0b = pk[u0 >> 2][2 * (u0 & 3) + 1];
                const unsigned P1a = pk[u1 >> 2][2 * (u1 & 3)];
                const unsigned P1b = pk[u1 >> 2][2 * (u1 & 3) + 1];
                const unsigned X1 = hh ? P0a : P1a;
                const unsigned X2 = hh ? P0b : P1b;
                const unsigned Y1 = __shfl_xor(X1, 32);
                const unsigned Y2 = __shfl_xor(X2, 32);
                unsigned dw[4];
                dw[0] = hh ? Y1 : P0a;
                dw[1] = hh ? Y2 : P0b;
                dw[2] = hh ? P1a : Y1;
                dw[3] = hh ? P1b : Y2;
                short8 pb = *reinterpret_cast<short8*>(dw);
                __builtin_amdgcn_s_setprio(1);
                of[s][0] = MFMA32(va[0][kc], pb, of[s][0]);
                of[s][1] = MFMA32(va[1][kc], pb, of[s][1]);
                __builtin_amdgcn_s_setprio(0);
            }
        }

        // write next tile into the other buffer (loads landed during compute)
        if (have_next) {
            *(uint4*)&Kl[cur ^ 1][srow][scol]      = kr0;
            *(uint4*)&Kl[cur ^ 1][srow + 32][scol] = kr1;
            *(uint4*)&Vl[cur ^ 1][srow][scol]      = vr0;
            *(uint4*)&Vl[cur ^ 1][srow + 32][scol] = vr1;
        }
        __syncthreads();   // all waves done reading cur; buf cur^1 visible
        cur ^= 1;
    }

    // store unnormalized partials (rows packed to TT per (z,bh))
    #pragma unroll
    for (int s = 0; s < 2; s++) {
        const int qrow = q0 + s * 32 + q31;
        if (qrow >= TT) continue;
        bf16* orow = OP + ((size_t)(z * BH + bh) * TT + qrow) * DH;
        #pragma unroll
        for (int dt = 0; dt < 2; dt++)
            #pragma unroll
            for (int p = 0; p < 4; p++) {
                const int d = dt * 32 + 8 * p + 4 * hh;
                unsigned lo = pack2(of[s][dt][4 * p], of[s][dt][4 * p + 1]);
                unsigned hi = pack2(of[s][dt][4 * p + 2], of[s][dt][4 * p + 3]);
                uint2 st = {lo, hi};
                *(uint2*)(orow + d) = st;
            }
        if (hh == 0) {
            float2 ml = {m2[s], lsum[s]};
            *(float2*)&ML[((size_t)(z * BH + bh) * TT + qrow) * 2] = ml;
        }
    }
}

// ---------------------------------------------------------------------------
// K3b: merge the split-K partials -> att (bf16, head-major cols).
// ---------------------------------------------------------------------------
__global__ __launch_bounds__(256)
void merge(const bf16* __restrict__ OP, const float* __restrict__ ML,
           bf16* __restrict__ att)
{
    const int idx = blockIdx.x * 256 + threadIdx.x;
    if (idx >= BH * TT * 16) return;
    const int quad = idx & 15;
    const int pair = idx >> 4;
    const int bh = pair / TT, row = pair % TT;
    const int b = bh / HH, h = bh % HH;
    const int d0 = quad * 4;

    float2 ml[NSPL];
    #pragma unroll
    for (int z = 0; z < NSPL; z++)
        ml[z] = *(const float2*)&ML[((size_t)(z * BH + bh) * TT + row) * 2];
    float M = ml[0].x;
    #pragma unroll
    for (int z = 1; z < NSPL; z++) M = fmaxf(M, ml[z].x);
    float wz[NSPL], den = 0.f;
    #pragma unroll
    for (int z = 0; z < NSPL; z++) {
        wz[z] = __builtin_amdgcn_exp2f(ml[z].x - M);
        den += ml[z].y * wz[z];
    }
    const float inv = 1.f / den;

    float o0 = 0.f, o1 = 0.f, o2 = 0.f, o3 = 0.f;
    #pragma unroll
    for (int z = 0; z < NSPL; z++) {
        const float s = wz[z] * inv;
        const uint2 a = *(const uint2*)&OP[((size_t)(z * BH + bh) * TT + row) * DH + d0];
        o0 += bu2f(a.x & 0xffffu) * s;
        o1 += bu2f(a.x >> 16)     * s;
        o2 += bu2f(a.y & 0xffffu) * s;
        o3 += bu2f(a.y >> 16)     * s;
    }
    uint2 st = {pack2(o0, o1), pack2(o2, o3)};
    *(uint2*)&att[((size_t)(b * TT + row) * CC) + h * DH + d0] = st;
}

// ---------------------------------------------------------------------------
// K4: output projection GEMM + bias, 128-row m-tiles, fp32 out.
// ---------------------------------------------------------------------------
__global__ __launch_bounds__(256)
void out_gemm(const bf16* __restrict__ att, const bf16* __restrict__ Wo_bf,
              const float* __restrict__ bo, float* __restrict__ out)
{
    const int m0 = blockIdx.x * 128;
    const int n0 = blockIdx.y * 64;
    const int w = threadIdx.x >> 6, lane = threadIdx.x & 63;
    const int lm = lane & 15, q4 = lane >> 4;

    const size_t ar0 = (size_t)(m0 + w * 16 + lm) * CC;
    floatx4 acc[2][4];
    #pragma unroll
    for (int st = 0; st < 2; st++)
        #pragma unroll
        for (int n = 0; n < 4; n++) acc[st][n] = (floatx4){0.f, 0.f, 0.f, 0.f};

    #pragma unroll 4
    for (int kc = 0; kc < CC / 32; kc++) {
        short8 a0 = *(const short8*)(att + ar0 + kc * 32 + q4 * 8);
        short8 a1 = *(const short8*)(att + ar0 + (size_t)64 * CC + kc * 32 + q4 * 8);
        #pragma unroll
        for (int n = 0; n < 4; n++) {
            short8 bfr = *(const short8*)(Wo_bf + (size_t)(n0 + n * 16 + lm) * CC + kc * 32 + q4 * 8);
            acc[0][n] = MFMA16(a0, bfr, acc[0][n]);
            acc[1][n] = MFMA16(a1, bfr, acc[1][n]);
        }
    }

    #pragma unroll
    for (int st = 0; st < 2; st++)
        #pragma unroll
        for (int n = 0; n < 4; n++) {
            const int o = n0 + n * 16 + lm;
            const float bias = bo[o];
            #pragma unroll
            for (int r = 0; r < 4; r++) {
                const int m = m0 + st * 64 + w * 16 + q4 * 4 + r;
                if (m < MF) out[(size_t)m * CC + o] = acc[st][n][r] + bias;
            }
        }
}

// ---------------------------------------------------------------------------
extern "C" void kernel_launch(void* const* d_in, const int* in_sizes, int n_in,
                              void* d_out, int out_size, void* d_ws, size_t ws_size,
                              hipStream_t stream)
{
    const float* x  = (const float*)d_in[0];
    const float* kq = (const float*)d_in[3];
    const float* kk = (const float*)d_in[4];
    const float* kv = (const float*)d_in[5];
    const float* gq = (const float*)d_in[6];
    const float* bq = (const float*)d_in[7];
    const float* mq = (const float*)d_in[8];
    const float* vq = (const float*)d_in[9];
    const float* gk = (const float*)d_in[10];
    const float* bk = (const float*)d_in[11];
    const float* mk = (const float*)d_in[12];
    const float* vk = (const float*)d_in[13];
    const float* gv = (const float*)d_in[14];
    const float* bv = (const float*)d_in[15];
    const float* mv = (const float*)d_in[16];
    const float* vv = (const float*)d_in[17];
    const float* Wq = (const float*)d_in[18];
    const float* Wk = (const float*)d_in[19];
    const float* Wv = (const float*)d_in[20];
    const float* Wo = (const float*)d_in[21];
    const float* bo = (const float*)d_in[22];

    char* ws = (char*)d_ws;
    const size_t SZ_CONV = (size_t)MP * CC * 2;        // 7,176,192
    const size_t SZ_Q    = (size_t)BH * TQP * DH * 2;  // 7,864,320
    const size_t SZ_K    = (size_t)BH * TP * DH * 2;   // 7,274,496
    const size_t SZ_W    = (size_t)CC * CC * 2;        //   294,912
    size_t off = 0;
    bf16* cq   = (bf16*)(ws + off); off += SZ_CONV;
    bf16* ck   = (bf16*)(ws + off); off += SZ_CONV;
    bf16* cv   = (bf16*)(ws + off); off += SZ_CONV;
    bf16* qb   = (bf16*)(ws + off); off += SZ_Q;
    bf16* kb   = (bf16*)(ws + off); off += SZ_K;
    bf16* vTb  = (bf16*)(ws + off); off += SZ_K;
    bf16* attb = (bf16*)(ws + off); off += SZ_CONV;
    bf16* wqb  = (bf16*)(ws + off); off += SZ_W;
    bf16* wkb  = (bf16*)(ws + off); off += SZ_W;
    bf16* wvb  = (bf16*)(ws + off); off += SZ_W;
    bf16* wob  = (bf16*)(ws + off); off += SZ_W;
    // flash partials: OP aliases cq..cv (dead after qkv_gemm), ML in tail
    // NSPL*BH*TT*DH*2 = 14,161,920 <= 3*SZ_CONV = 21,528,576
    bf16*  OP = (bf16*)ws;
    float* ML = (float*)(ws + off); off += (size_t)NSPL * BH * TT * 2 * 4;

    conv_bn<<<BN * 289, 384, 0, stream>>>(x, kq, kk, kv,
                                          gq, bq, mq, vq,
                                          gk, bk, mk, vk,
                                          gv, bv, mv, vv,
                                          Wq, Wk, Wv, Wo,
                                          wqb, wkb, wvb, wob,
                                          cq, ck, cv);
    qkv_gemm<<<dim3(40, 18), 256, 0, stream>>>(cq, ck, cv, wqb, wkb, wvb, qb, kb, vTb);
    flash<<<QTI * NSPL * BH, 256, 0, stream>>>(qb, kb, vTb, OP, ML);
    merge<<<(BH * TT * 16 + 255) / 256, 256, 0, stream>>>(OP, ML, attb);
    out_gemm<<<dim3(MB2, 6), 256, 0, stream>>>(attb, wob, bo, (float*)d_out);
}